// Round 1
// baseline (734.470 us; speedup 1.0000x reference)
//
#include <hip/hip_runtime.h>
#include <stdint.h>

#define E_NUM 1000000
#define NNODES 100000

typedef __attribute__((ext_vector_type(8))) short short8;
typedef __attribute__((ext_vector_type(4))) short short4v;
typedef __attribute__((ext_vector_type(4))) float f32x4;

// ws layout (bytes)
static constexpr size_t OFF_ZU = 0;                       // 100000*128*2 = 25,600,000
static constexpr size_t OFF_ZB = 25600000;                // + 25,600,000
static constexpr size_t OFF_W1 = 51200000;                // 256*256*2 = 131072
static constexpr size_t OFF_W2 = 51200000 + 131072;
static constexpr size_t OFF_W3 = 51200000 + 262144;       // padded [16][256] bf16 = 8192

__device__ __forceinline__ uint16_t f2bf(float x) {
  union { float f; uint32_t u; } a; a.f = x;
  uint32_t r = a.u + 0x7fffu + ((a.u >> 16) & 1u);  // round-to-nearest-even
  return (uint16_t)(r >> 16);
}

__global__ void conv_z_kernel(const float* __restrict__ zu, const float* __restrict__ zb,
                              uint16_t* __restrict__ ou, uint16_t* __restrict__ ob) {
  const int64_t n4 = (int64_t)NNODES * 128 / 4;  // 3,200,000 float4s per table
  for (int64_t i = (int64_t)blockIdx.x * blockDim.x + threadIdx.x; i < n4;
       i += (int64_t)gridDim.x * blockDim.x) {
    float4 u = reinterpret_cast<const float4*>(zu)[i];
    float4 b = reinterpret_cast<const float4*>(zb)[i];
    short4v pu, pb;
    pu[0] = (short)f2bf(u.x); pu[1] = (short)f2bf(u.y);
    pu[2] = (short)f2bf(u.z); pu[3] = (short)f2bf(u.w);
    pb[0] = (short)f2bf(b.x); pb[1] = (short)f2bf(b.y);
    pb[2] = (short)f2bf(b.z); pb[3] = (short)f2bf(b.w);
    *reinterpret_cast<short4v*>(ou + i * 4) = pu;
    *reinterpret_cast<short4v*>(ob + i * 4) = pb;
  }
}

__global__ void conv_w_kernel(const float* __restrict__ W1, const float* __restrict__ W2,
                              const float* __restrict__ W3,
                              uint16_t* __restrict__ o1, uint16_t* __restrict__ o2,
                              uint16_t* __restrict__ o3) {
  const int i = blockIdx.x * 256 + threadIdx.x;
  if (i < 65536) {
    o1[i] = f2bf(W1[i]);
    o2[i] = f2bf(W2[i]);
  }
  if (i < 4096) {  // W3 padded from [10][256] to [16][256] with zero rows
    const int r = i >> 8, c = i & 255;
    o3[i] = (r < 10) ? f2bf(W3[r * 256 + c]) : (uint16_t)0;
  }
}

// Fused MLP: 64 edges per block, 4 waves.
// sZ: gather tile [user 64x128 | book 64x128] bf16 (32 KB), reused as H2 [64][256] bf16.
// sH: H1 [64][256] bf16 (32 KB). All LDS tiles XOR-swizzled: byte ^= (row&7)<<4.
// GEMMs computed swapped (D = W * Z^T) so C-fragments are row-contiguous per edge.
__global__ __launch_bounds__(256, 2) void edge_mlp_kernel(
    const uint16_t* __restrict__ zu, const uint16_t* __restrict__ zb,
    const int* __restrict__ eidx,
    const uint16_t* __restrict__ w1, const uint16_t* __restrict__ w2,
    const uint16_t* __restrict__ w3,
    const float* __restrict__ b1, const float* __restrict__ b2,
    const float* __restrict__ b3v,
    float* __restrict__ out)
{
  __shared__ __align__(16) unsigned char sZ[64 * 512];
  __shared__ __align__(16) unsigned char sH[64 * 512];

  const int tid = (int)threadIdx.x;
  const int w  = tid >> 6;
  const int l  = tid & 63;
  const int lg = l >> 4;   // 0..3
  const int lc = l & 15;   // 0..15
  const int e0 = (int)blockIdx.x * 64;

  // ---- gather: wave w stages edges [w*16, w*16+16); 4 edges per global_load_lds ----
  #pragma unroll
  for (int i = 0; i < 4; ++i) {
    const int m = w * 16 + i * 4 + lg;   // row within tile (per-lane)
    const int e = e0 + m;
    int nu = eidx[e];
    int nb = eidx[E_NUM + e];
    nu = (nu < 0) ? 0 : (nu >= NNODES ? NNODES - 1 : nu);
    nb = (nb < 0) ? 0 : (nb >= NNODES ? NNODES - 1 : nb);
    const int c = lc ^ (m & 7);          // pre-swizzled source chunk
    const uint16_t* gu = zu + (size_t)nu * 128 + c * 8;
    const uint16_t* gb = zb + (size_t)nb * 128 + c * 8;
    unsigned char* du = sZ + (w * 16 + i * 4) * 256;            // wave-uniform dest base
    unsigned char* db = sZ + 64 * 256 + (w * 16 + i * 4) * 256;
    __builtin_amdgcn_global_load_lds((const __attribute__((address_space(1))) void*)gu,
                                     (__attribute__((address_space(3))) void*)du, 16, 0, 0);
    __builtin_amdgcn_global_load_lds((const __attribute__((address_space(1))) void*)gb,
                                     (__attribute__((address_space(3))) void*)db, 16, 0, 0);
  }
  asm volatile("s_waitcnt vmcnt(0)" ::: "memory");
  __syncthreads();

  const int nbase = w * 64;  // this wave's hidden-unit slice
  f32x4 acc[4][4];
  #pragma unroll
  for (int nt = 0; nt < 4; ++nt)
    #pragma unroll
    for (int mt = 0; mt < 4; ++mt)
      acc[nt][mt] = (f32x4){0.f, 0.f, 0.f, 0.f};

  // ---- GEMM1: H1^T = W1 * Z^T ----
  #pragma unroll
  for (int k0 = 0; k0 < 8; ++k0) {
    const int kk = k0 * 32 + lg * 8;
    short8 afrag[4];
    #pragma unroll
    for (int nt = 0; nt < 4; ++nt)
      afrag[nt] = *reinterpret_cast<const short8*>(w1 + (size_t)(nbase + nt * 16 + lc) * 256 + kk);
    const int kb = kk * 2;
    short8 bfrag[4];
    #pragma unroll
    for (int mt = 0; mt < 4; ++mt) {
      const int m = mt * 16 + lc;
      int off;
      if (kb < 256) off = m * 256 + (kb ^ ((m & 7) << 4));
      else          off = 64 * 256 + m * 256 + ((kb - 256) ^ ((m & 7) << 4));
      bfrag[mt] = *reinterpret_cast<const short8*>(sZ + off);
    }
    #pragma unroll
    for (int nt = 0; nt < 4; ++nt)
      #pragma unroll
      for (int mt = 0; mt < 4; ++mt)
        acc[nt][mt] = __builtin_amdgcn_mfma_f32_16x16x32_bf16(afrag[nt], bfrag[mt], acc[nt][mt], 0, 0, 0);
  }

  // ---- epilogue 1: bias + relu + bf16 -> sH (row-contiguous 8B writes) ----
  #pragma unroll
  for (int nt = 0; nt < 4; ++nt) {
    const int n0 = nbase + nt * 16 + lg * 4;
    const float q0 = b1[n0], q1 = b1[n0 + 1], q2 = b1[n0 + 2], q3 = b1[n0 + 3];
    #pragma unroll
    for (int mt = 0; mt < 4; ++mt) {
      const int m = mt * 16 + lc;
      short4v pk;
      pk[0] = (short)f2bf(fmaxf(acc[nt][mt][0] + q0, 0.f));
      pk[1] = (short)f2bf(fmaxf(acc[nt][mt][1] + q1, 0.f));
      pk[2] = (short)f2bf(fmaxf(acc[nt][mt][2] + q2, 0.f));
      pk[3] = (short)f2bf(fmaxf(acc[nt][mt][3] + q3, 0.f));
      const int off = m * 512 + ((n0 * 2) ^ ((m & 7) << 4));
      *reinterpret_cast<short4v*>(sH + off) = pk;
    }
  }
  __syncthreads();

  // ---- GEMM2: H2^T = W2 * H1^T ----
  #pragma unroll
  for (int nt = 0; nt < 4; ++nt)
    #pragma unroll
    for (int mt = 0; mt < 4; ++mt)
      acc[nt][mt] = (f32x4){0.f, 0.f, 0.f, 0.f};
  #pragma unroll
  for (int k0 = 0; k0 < 8; ++k0) {
    const int kk = k0 * 32 + lg * 8;
    short8 afrag[4];
    #pragma unroll
    for (int nt = 0; nt < 4; ++nt)
      afrag[nt] = *reinterpret_cast<const short8*>(w2 + (size_t)(nbase + nt * 16 + lc) * 256 + kk);
    const int kb = kk * 2;
    short8 bfrag[4];
    #pragma unroll
    for (int mt = 0; mt < 4; ++mt) {
      const int m = mt * 16 + lc;
      bfrag[mt] = *reinterpret_cast<const short8*>(sH + m * 512 + (kb ^ ((m & 7) << 4)));
    }
    #pragma unroll
    for (int nt = 0; nt < 4; ++nt)
      #pragma unroll
      for (int mt = 0; mt < 4; ++mt)
        acc[nt][mt] = __builtin_amdgcn_mfma_f32_16x16x32_bf16(afrag[nt], bfrag[mt], acc[nt][mt], 0, 0, 0);
  }

  // ---- epilogue 2: bias + relu + bf16 -> sZ reused as H2 [64][512B] ----
  #pragma unroll
  for (int nt = 0; nt < 4; ++nt) {
    const int n0 = nbase + nt * 16 + lg * 4;
    const float q0 = b2[n0], q1 = b2[n0 + 1], q2 = b2[n0 + 2], q3 = b2[n0 + 3];
    #pragma unroll
    for (int mt = 0; mt < 4; ++mt) {
      const int m = mt * 16 + lc;
      short4v pk;
      pk[0] = (short)f2bf(fmaxf(acc[nt][mt][0] + q0, 0.f));
      pk[1] = (short)f2bf(fmaxf(acc[nt][mt][1] + q1, 0.f));
      pk[2] = (short)f2bf(fmaxf(acc[nt][mt][2] + q2, 0.f));
      pk[3] = (short)f2bf(fmaxf(acc[nt][mt][3] + q3, 0.f));
      const int off = m * 512 + ((n0 * 2) ^ ((m & 7) << 4));
      *reinterpret_cast<short4v*>(sZ + off) = pk;
    }
  }
  __syncthreads();

  // ---- GEMM3: O^T = W3pad * H2^T ; wave w owns edges [w*16, w*16+16) ----
  f32x4 acc3 = (f32x4){0.f, 0.f, 0.f, 0.f};
  const int m3 = w * 16 + lc;
  #pragma unroll
  for (int k0 = 0; k0 < 8; ++k0) {
    const int kk = k0 * 32 + lg * 8;
    short8 a3 = *reinterpret_cast<const short8*>(w3 + (size_t)lc * 256 + kk);
    const int kb = kk * 2;
    short8 bf = *reinterpret_cast<const short8*>(sZ + m3 * 512 + (kb ^ ((m3 & 7) << 4)));
    acc3 = __builtin_amdgcn_mfma_f32_16x16x32_bf16(a3, bf, acc3, 0, 0, 0);
  }

  // ---- log_softmax over n=0..9 ; lane holds n = lg*4 + r for edge m3 ----
  float vv[4];
  float mx = -3.0e38f;
  #pragma unroll
  for (int r = 0; r < 4; ++r) {
    const int n = lg * 4 + r;
    const float x = acc3[r] + ((n < 10) ? b3v[n] : 0.f);
    vv[r] = x;
    if (n < 10) mx = fmaxf(mx, x);
  }
  mx = fmaxf(mx, __shfl_xor(mx, 16));
  mx = fmaxf(mx, __shfl_xor(mx, 32));
  float s = 0.f;
  #pragma unroll
  for (int r = 0; r < 4; ++r) {
    const int n = lg * 4 + r;
    if (n < 10) s += __expf(vv[r] - mx);
  }
  s += __shfl_xor(s, 16);
  s += __shfl_xor(s, 32);
  const float lse = mx + __logf(s);

  const int e = e0 + w * 16 + lc;
  float* po = out + (size_t)e * 10;
  if (lg == 0) {
    *reinterpret_cast<float2*>(po)     = make_float2(vv[0] - lse, vv[1] - lse);
    *reinterpret_cast<float2*>(po + 2) = make_float2(vv[2] - lse, vv[3] - lse);
  } else if (lg == 1) {
    *reinterpret_cast<float2*>(po + 4) = make_float2(vv[0] - lse, vv[1] - lse);
    *reinterpret_cast<float2*>(po + 6) = make_float2(vv[2] - lse, vv[3] - lse);
  } else if (lg == 2) {
    *reinterpret_cast<float2*>(po + 8) = make_float2(vv[0] - lse, vv[1] - lse);
  }
}

extern "C" void kernel_launch(void* const* d_in, const int* in_sizes, int n_in,
                              void* d_out, int out_size, void* d_ws, size_t ws_size,
                              hipStream_t stream) {
  const float* z_user = (const float*)d_in[0];
  const float* z_book = (const float*)d_in[1];
  const int*   eidx   = (const int*)d_in[2];
  const float* W1     = (const float*)d_in[3];
  const float* b1     = (const float*)d_in[4];
  const float* W2     = (const float*)d_in[5];
  const float* b2     = (const float*)d_in[6];
  const float* W3     = (const float*)d_in[7];
  const float* b3     = (const float*)d_in[8];
  float* out = (float*)d_out;

  uint8_t* ws = (uint8_t*)d_ws;
  uint16_t* zu_b = (uint16_t*)(ws + OFF_ZU);
  uint16_t* zb_b = (uint16_t*)(ws + OFF_ZB);
  uint16_t* w1_b = (uint16_t*)(ws + OFF_W1);
  uint16_t* w2_b = (uint16_t*)(ws + OFF_W2);
  uint16_t* w3_b = (uint16_t*)(ws + OFF_W3);

  conv_z_kernel<<<2048, 256, 0, stream>>>(z_user, z_book, zu_b, zb_b);
  conv_w_kernel<<<256, 256, 0, stream>>>(W1, W2, W3, w1_b, w2_b, w3_b);
  edge_mlp_kernel<<<E_NUM / 64, 256, 0, stream>>>(zu_b, zb_b, eidx,
                                                  w1_b, w2_b, w3_b,
                                                  b1, b2, b3, out);
}